// Round 10
// baseline (290.288 us; speedup 1.0000x reference)
//
#include <hip/hip_runtime.h>
#include <math.h>

#define NIMG 32
#define NB3  771             // 257 rings * 3 sums
#define PI_F 3.14159265358979323846f
#define GRID 512             // 2 blocks/CU co-resident by construction

// ---------------------------------------------------------------------------
__device__ __forceinline__ float2 cadd(float2 a, float2 b){ return make_float2(a.x+b.x, a.y+b.y); }
__device__ __forceinline__ float2 csub(float2 a, float2 b){ return make_float2(a.x-b.x, a.y-b.y); }
__device__ __forceinline__ float2 cmul(float2 a, float2 b){ return make_float2(a.x*b.x - a.y*b.y, a.x*b.y + a.y*b.x); }
__device__ __forceinline__ float2 cmul_mi(float2 a){ return make_float2(a.y, -a.x); }   // * (-i)
__device__ __forceinline__ float2 tw(const float2* T, int m){ return T[m + (m >> 3)]; }
__device__ __forceinline__ int   swz(int pos){ return pos + (pos >> 3); }

// 8-point DFT (DIF, natural-order outputs), e^{-2pi i/8} convention
__device__ __forceinline__ void dft8(float2* x) {
    const float c = 0.70710678118654752f;
    float2 u0 = cadd(x[0], x[4]), u1 = cadd(x[1], x[5]);
    float2 u2 = cadd(x[2], x[6]), u3 = cadd(x[3], x[7]);
    float2 v0 = csub(x[0], x[4]);
    float2 d1 = csub(x[1], x[5]);
    float2 v1 = make_float2(c*(d1.x + d1.y), c*(d1.y - d1.x));
    float2 d2 = csub(x[2], x[6]);
    float2 v2 = make_float2(d2.y, -d2.x);
    float2 d3 = csub(x[3], x[7]);
    float2 v3 = make_float2(-c*(d3.x - d3.y), -c*(d3.x + d3.y));
    float2 e0 = cadd(u0,u2), e1 = cadd(u1,u3);
    float2 f0 = csub(u0,u2), f1 = cmul_mi(csub(u1,u3));
    float2 g0 = cadd(v0,v2), g1 = cadd(v1,v3);
    float2 h0 = csub(v0,v2), h1 = cmul_mi(csub(v1,v3));
    x[0] = cadd(e0,e1); x[4] = csub(e0,e1);
    x[2] = cadd(f0,f1); x[6] = csub(f0,f1);
    x[1] = cadd(g0,g1); x[5] = csub(g0,g1);
    x[3] = cadd(h0,h1); x[7] = csub(h0,h1);
}

// ---------------------------------------------------------------------------
// Per-wave 512-pt radix-8 DIF FFT, barrier-free (wave-private 576-slot LDS
// scratch; one wave's LDS ops execute in order). Thread J enters with
// X[q] = x[J + 64q], exits with X[k] = F(64k + r), r = 8*(J&7) + (J>>3).
// ---------------------------------------------------------------------------
__device__ __forceinline__ void wave_fft512(float2* X, float2* Sw,
                                            const float2* T, int J) {
    dft8(X);
#pragma unroll
    for (int k = 1; k < 8; ++k) X[k] = cmul(X[k], tw(T, J * k));
    const int jj = J + (J >> 3);
#pragma unroll
    for (int k = 0; k < 8; ++k) Sw[jj + 72*k] = X[k];

    const int j2 = J & 7;
    const int bb = 72 * (J >> 3) + j2;
#pragma unroll
    for (int q = 0; q < 8; ++q) X[q] = Sw[bb + 9*q];
    dft8(X);
#pragma unroll
    for (int k = 1; k < 8; ++k) X[k] = cmul(X[k], tw(T, 8 * j2 * k));
#pragma unroll
    for (int k = 0; k < 8; ++k) Sw[bb + 9*k] = X[k];

#pragma unroll
    for (int q = 0; q < 8; ++q) X[q] = Sw[9*J + q];
    dft8(X);
}

// ---------------------------------------------------------------------------
// Manual grid barrier: arrive (device-scope atomicAdd) + agent-scope relaxed
// spin + release/acquire fences. All 512 blocks are co-resident
// (grid = 2 blocks/CU, launch_bounds enforces schedulability).
// ---------------------------------------------------------------------------
__device__ __forceinline__ void gbar(unsigned* bar, int idx) {
    __syncthreads();
    if (threadIdx.x == 0) {
        __threadfence();                                   // release
        atomicAdd(&bar[idx], 1u);
        while (__hip_atomic_load(&bar[idx], __ATOMIC_RELAXED,
                                 __HIP_MEMORY_SCOPE_AGENT) < GRID) {
            __builtin_amdgcn_s_sleep(2);
        }
        __threadfence();                                   // acquire
    }
    __syncthreads();
}

// ---------------------------------------------------------------------------
// Single persistent kernel:
//   P1: row FFTs -> transposed Zt[kx][y]; also zero ring sums & out
//   barrier
//   P2: col FFT + ring binning -> 8 shared slices/image (HW float atomics)
//   barrier
//   P3: finalize (32 blocks, one HW atomic each into out[0])
// ---------------------------------------------------------------------------
__global__ __launch_bounds__(256, 2)
void frc_mega(const float* __restrict__ xr, const float* __restrict__ yr,
              float2* __restrict__ Zt, float* __restrict__ sums,
              unsigned* __restrict__ bar, float* __restrict__ out) {
    __shared__ float2 S[8 * 576];      // 36,864 B
    __shared__ float2 T[576];          //  4,608 B
    __shared__ float  bins[258 * 3];   //  3,096 B
    __shared__ float  red[4];
    const int t = threadIdx.x, w = t >> 6, J = t & 63;
    const int r = ((J & 7) << 3) | (J >> 3);   // digit-reverse of lane

#pragma unroll
    for (int i = 0; i < 2; ++i) {
        const int m = t + 256 * i;
        float s, c;
        __sincosf(-2.0f * PI_F * (float)m / 512.0f, &s, &c);
        T[m + (m >> 3)] = make_float2(c, s);
    }
    // zero ring sums (harness poisons ws each call) and the output scalar
    for (int i = blockIdx.x * 256 + t; i < NIMG * 8 * NB3; i += GRID * 256)
        sums[i] = 0.0f;
    if (blockIdx.x == 0 && t == 0) atomicExch(out, 0.0f);
    __syncthreads();

    // ================= P1: row FFTs, transposed write =================
    for (int u = blockIdx.x; u < 2048; u += GRID) {
        const int im = u >> 6, grp = u & 63;
        const size_t b0 = ((size_t)(im * 512 + grp * 8 + w)) << 9;
        const size_t b1 = b0 + 2048;           // +4 rows
        float2 X0[8], X1[8];
#pragma unroll
        for (int q = 0; q < 8; ++q) {
            X0[q] = make_float2(xr[b0 + J + 64*q], yr[b0 + J + 64*q]);
            X1[q] = make_float2(xr[b1 + J + 64*q], yr[b1 + J + 64*q]);
        }
        float2* Sw = S + w * 576;
        wave_fft512(X0, Sw, T, J);
        wave_fft512(X1, Sw, T, J);

#pragma unroll
        for (int k = 0; k < 8; ++k) Sw[64*k + r] = X0[k];
        __syncthreads();
        float2 eA[4], eB[4];
#pragma unroll
        for (int j = 0; j < 4; ++j) { eA[j] = S[j*576 + t]; eB[j] = S[j*576 + t + 256]; }
        __syncthreads();
#pragma unroll
        for (int k = 0; k < 8; ++k) Sw[64*k + r] = X1[k];
        __syncthreads();

        const size_t zb = ((size_t)im << 18) + (grp << 3);
        {
            float4* o = (float4*)(Zt + zb + ((size_t)t << 9));
            float2 f0 = S[0*576 + t], f1 = S[1*576 + t];
            float2 f2 = S[2*576 + t], f3 = S[3*576 + t];
            o[0] = make_float4(eA[0].x, eA[0].y, eA[1].x, eA[1].y);
            o[1] = make_float4(eA[2].x, eA[2].y, eA[3].x, eA[3].y);
            o[2] = make_float4(f0.x, f0.y, f1.x, f1.y);
            o[3] = make_float4(f2.x, f2.y, f3.x, f3.y);
        }
        {
            float4* o = (float4*)(Zt + zb + ((size_t)(t + 256) << 9));
            float2 f0 = S[0*576 + t + 256], f1 = S[1*576 + t + 256];
            float2 f2 = S[2*576 + t + 256], f3 = S[3*576 + t + 256];
            o[0] = make_float4(eB[0].x, eB[0].y, eB[1].x, eB[1].y);
            o[1] = make_float4(eB[2].x, eB[2].y, eB[3].x, eB[3].y);
            o[2] = make_float4(f0.x, f0.y, f1.x, f1.y);
            o[3] = make_float4(f2.x, f2.y, f3.x, f3.y);
        }
        __syncthreads();     // protect S before next unit's FFT scratch writes
    }

    gbar(bar, 0);

    // ================= P2: col FFT + rings =================
    const float scale = 1.0f / (512.0f * 512.0f);
    for (int u = blockIdx.x; u < 2048; u += GRID) {
        const int im = u >> 6, g = u & 63;
        const int p = 4 * g + w;
        for (int i = t; i < 258 * 3; i += 256) bins[i] = 0.0f;

        const int c0 = (p == 0) ? 0   : p;
        const int c1 = (p == 0) ? 256 : 512 - p;
        const float2* rp0 = Zt + ((size_t)im << 18) + ((size_t)c0 << 9);
        const float2* rp1 = Zt + ((size_t)im << 18) + ((size_t)c1 << 9);
        float2 X0[8], X1[8];
#pragma unroll
        for (int q = 0; q < 8; ++q) { X0[q] = rp0[J + 64*q]; X1[q] = rp1[J + 64*q]; }
        __syncthreads();                       // bins zeroed everywhere

        float2* A = S + (2*w) * 576;
        float2* B = A + 576;
        const int pk = r + (r >> 3);           // swz(64k + r) = 72k + pk
        wave_fft512(X0, A, T, J);
#pragma unroll
        for (int k = 0; k < 8; ++k) A[72*k + pk] = X0[k];    // park natural order
        wave_fft512(X1, B, T, J);
#pragma unroll
        for (int k = 0; k < 8; ++k) B[72*k + pk] = X1[k];

        auto pix = [&](float2 zk, float2 zm, float& av, float& c1v, float& c2v) {
            float f1r = 0.5f * (zk.x + zm.x) * scale;
            float f1i = 0.5f * (zk.y - zm.y) * scale;
            float f2r = 0.5f * (zk.y + zm.y) * scale;
            float f2i = 0.5f * (zm.x - zk.x) * scale;
            av  = f1r * f2r + f1i * f2i;
            c1v = f1r * f1r + f1i * f1i;
            c2v = f2r * f2r + f2i * f2i;
        };
        auto flush = [&](int ring, float a, float b, float c) {
            if (ring >= 0 && ring <= 256) {
                unsafeAtomicAdd(&bins[ring*3+0], a);
                unsafeAtomicAdd(&bins[ring*3+1], b);
                unsafeAtomicAdd(&bins[ring*3+2], c);
            }
        };

        if (p == 0) {
            int cur0 = -1, cur1 = -1;
            float a0 = 0, b0 = 0, c0v = 0, a1 = 0, b1 = 0, c1v = 0;
#pragma unroll
            for (int i = 0; i < 8; ++i) {
                const int ky  = 8*J + i;
                const int kyp = (512 - ky) & 511;
                float2 zk0 = A[swz(ky)], zm0 = A[swz(kyp)];
                float2 zk1 = B[swz(ky)], zm1 = B[swz(kyp)];
                const float fk = (ky < 256) ? (float)ky : (float)(ky - 512);
                float av, cv, dv;
                pix(zk0, zm0, av, cv, dv);                 // col 0, fy = 0
                int rr = (int)rintf(fabsf(fk)); if (rr > 256) rr = 257;
                if (rr != cur0) { flush(cur0, a0, b0, c0v); cur0 = rr; a0 = av; b0 = cv; c0v = dv; }
                else            { a0 += av; b0 += cv; c0v += dv; }
                pix(zk1, zm1, av, cv, dv);                 // col 256, fy = 256
                rr = (int)rintf(sqrtf(fk*fk + 65536.0f)); if (rr > 256) rr = 257;
                if (rr != cur1) { flush(cur1, a1, b1, c1v); cur1 = rr; a1 = av; b1 = cv; c1v = dv; }
                else            { a1 += av; b1 += cv; c1v += dv; }
            }
            flush(cur0, a0, b0, c0v);
            flush(cur1, a1, b1, c1v);
        } else {
            const float fy2 = (float)p * (float)p;
            int curR = -1;
            float sA = 0, sB = 0, sC = 0;
#pragma unroll
            for (int i = 0; i < 8; ++i) {
                const int ky  = 8*J + i;
                const int kyp = (512 - ky) & 511;
                float2 zk = A[swz(ky)];          // P0[ky]
                float2 zm = B[swz(kyp)];         // P1[512-ky]
                float a1v, b1v, d1v, a2v, b2v, d2v;
                pix(zk, zm, a1v, b1v, d1v);      // (p, ky)         partner (512-p, 512-ky)
                pix(zm, zk, a2v, b2v, d2v);      // (512-p, 512-ky) partner (p, ky)
                const float fk = (ky < 256) ? (float)ky : (float)(ky - 512);
                int rr = (int)rintf(sqrtf(fk*fk + fy2)); if (rr > 256) rr = 257;
                const float aa = a1v + a2v, bb = b1v + b2v, cc = d1v + d2v;
                if (rr != curR) { flush(curR, sA, sB, sC); curR = rr; sA = aa; sB = bb; sC = cc; }
                else            { sA += aa; sB += bb; sC += cc; }
            }
            flush(curR, sA, sB, sC);
        }
        __syncthreads();                       // all deposits done
        float* dst = sums + (size_t)(im * 8 + (g & 7)) * NB3;
        for (int i = t; i < NB3; i += 256) unsafeAtomicAdd(&dst[i], bins[i]);
        __syncthreads();                       // flush reads done before re-zeroing
    }

    gbar(bar, 1);

    // ================= P3: finalize =================
    // C_i ring sums are exactly 0 by k -> -k antisymmetry; dropped.
    if (blockIdx.x < NIMG) {
        const int im = blockIdx.x;
        float acc = 0.0f;
        for (int rr = t; rr < 257; rr += 256) {
            float cr = 0.f, c1 = 0.f, c2 = 0.f;
#pragma unroll
            for (int s = 0; s < 8; ++s) {
                const float* pp = sums + (size_t)(im * 8 + s) * NB3 + rr * 3;
                cr += pp[0]; c1 += pp[1]; c2 += pp[2];
            }
            float frc = fabsf(cr) / (sqrtf(c1 * c2) + 1e-8f);
            float d = 1.0f - frc;
            acc += d * d;
        }
#pragma unroll
        for (int off = 32; off > 0; off >>= 1) acc += __shfl_down(acc, off);
        if ((t & 63) == 0) red[t >> 6] = acc;
        __syncthreads();
        if (t == 0)
            unsafeAtomicAdd(out, (red[0] + red[1] + red[2] + red[3]) *
                                 (1.0f / (257.0f * (float)NIMG)));
    }
}

// ---------------------------------------------------------------------------
extern "C" void kernel_launch(void* const* d_in, const int* in_sizes, int n_in,
                              void* d_out, int out_size, void* d_ws, size_t ws_size,
                              hipStream_t stream) {
    const float* xr = (const float*)d_in[0];   // output: 32x1x512x512 f32
    const float* yr = (const float*)d_in[1];   // target: 32x1x512x512 f32

    float2*   Zt   = (float2*)d_ws;                                 // 64 MiB
    float*    sums = (float*)((char*)d_ws + (((size_t)NIMG << 18) * sizeof(float2)));
    unsigned* bar  = (unsigned*)(sums + (size_t)NIMG * 8 * NB3);    // 2 uints
    float*    out  = (float*)d_out;

    hipMemsetAsync(bar, 0, 2 * sizeof(unsigned), stream);           // ws is poisoned each call

    frc_mega<<<dim3(GRID), dim3(256), 0, stream>>>(xr, yr, Zt, sums, bar, out);
}